// Round 11
// baseline (364.640 us; speedup 1.0000x reference)
//
#include <hip/hip_runtime.h>
#include <hip/hip_bf16.h>
#include <math.h>

// Problem constants (fixed by setup_inputs)
#define BB 4
#define NN 16384
#define SS 4096
#define D1 128
#define D2 256
#define C1 256   // mlp[0]
#define C2 128   // mlp[1]
#define MTOT (BB*NN)   // 65536

// knn decomposition. R10: pass1 distance-only; indices recovered by rescan
// (ballot first-occurrence == lax.top_k stable tie rule).
// R16: candidates wave-uniform -> s_load on the scalar pipe.
// R17: packed-f32 candidate pairs (v_pk_*_f32, per-component IEEE-identical).
// R18 (this round): QPT 2->4. R10 post-mortem: cutting VALU insts 30% left
// time unchanged -> NOT issue-bound; the invariant between R9/R10 is the
// 4KB/wave candidate stream through the scalar pipe. QPT=4 halves scalar
// bytes per query-work (32MB->16MB total). ILP preserved: 4 waves/SIMD x 4
// query chains = 16 chains/SIMD (same as 8x2).
#define QPT 4              // queries per thread
#define SCH 256            // candidates per chunk (4KB, K$/L2-resident)
#define NCH (SS/SCH)       // 16 chunks

typedef _Float16 f16x8 __attribute__((ext_vector_type(8)));
typedef float f32x4  __attribute__((ext_vector_type(4)));
typedef float f32x2  __attribute__((ext_vector_type(2)));

#define LPAD 40            // LDS row stride in fp16 elems (80B, 16B-aligned)
#define GSTRIDE 132        // f32 interp buffer row stride (528B: 16B-aligned, <=2-way banks)

// ---------------------------------------------------------------------------
// Pack xyz2 into {-2x, -2y, -2z, ||p||^2}: AoS float4 (for rescan's per-lane
// loads) AND SoA planes (for pass1's scalar-pipe packed pairs).
// Scaling by -2 is EXACT (power of two commutes with IEEE rounding), so
// d = (qq + cr2) + pw is bit-identical to the reference association
// d = (qq - 2*cr) + pw.
// ---------------------------------------------------------------------------
__global__ __launch_bounds__(256) void pack_kernel(
    const float* __restrict__ xyz2, float4* __restrict__ packed,
    float* __restrict__ pxp, float* __restrict__ pyp,
    float* __restrict__ pzp, float* __restrict__ pwp)
{
#pragma clang fp contract(off)
    int s = blockIdx.x * 256 + threadIdx.x;
    float px = xyz2[s*3+0], py = xyz2[s*3+1], pz = xyz2[s*3+2];
    float pp = (px*px + py*py) + pz*pz;
    float ax = px * -2.0f, ay = py * -2.0f, az = pz * -2.0f;
    packed[s] = make_float4(ax, ay, az, pp);
    pxp[s] = ax; pyp[s] = ay; pzp[s] = az; pwp[s] = pp;
}

// ---------------------------------------------------------------------------
// Convert W1, W2 to fp16 (RNE) once.
// ---------------------------------------------------------------------------
__global__ __launch_bounds__(256) void wcvt_kernel(
    const float* __restrict__ W1, const float* __restrict__ W2,
    _Float16* __restrict__ W1c, _Float16* __restrict__ W2c)
{
    int i = blockIdx.x * 256 + threadIdx.x;
    if (i < C1 * (D1 + D2)) W1c[i] = (_Float16)W1[i];
    if (i < C2 * C1)        W2c[i] = (_Float16)W2[i];
}

// ---------------------------------------------------------------------------
// 3-NN pass 1 (DISTANCE-ONLY, scalar-pipe candidates, packed-f32 pairs):
// exact fp32 distances (contract off, reference association), min/med3
// value network. Indices recovered exactly in knn3_rescan_kernel.
// HARD CONSTRAINT: never approximate the distance or the comparison.
// ---------------------------------------------------------------------------
__global__ __launch_bounds__(256, 8) void knn3_partial_kernel(
    const float* __restrict__ xyz1,
    const float* __restrict__ pxp, const float* __restrict__ pyp,
    const float* __restrict__ pzp, const float* __restrict__ pwp,
    float* __restrict__ pdist)
{
#pragma clang fp contract(off)
    const int qblocks = NN / (256 * QPT);            // 16
    const int b  = blockIdx.x / (qblocks * NCH);
    const int r  = blockIdx.x % (qblocks * NCH);
    const int qc = r / NCH;
    const int sc = r % NCH;

    // wave-uniform SoA plane pointers -> s_load (scalar pipe)
    const float* __restrict__ px = pxp + (size_t)b * SS + sc * SCH;
    const float* __restrict__ py = pyp + (size_t)b * SS + sc * SCH;
    const float* __restrict__ pz = pzp + (size_t)b * SS + sc * SCH;
    const float* __restrict__ pw = pwp + (size_t)b * SS + sc * SCH;

    f32x2 qx2[QPT], qy2[QPT], qz2[QPT], qq2[QPT];
    float e0[QPT], e1[QPT], e2[QPT];
#pragma unroll
    for (int q = 0; q < QPT; ++q) {
        int n = qc * (256 * QPT) + q * 256 + threadIdx.x;
        size_t m = (size_t)b * NN + n;
        float qx = xyz1[m*3+0], qy = xyz1[m*3+1], qz = xyz1[m*3+2];
        float qq = (qx*qx + qy*qy) + qz*qz;
        qx2[q] = (f32x2){qx, qx}; qy2[q] = (f32x2){qy, qy};
        qz2[q] = (f32x2){qz, qz}; qq2[q] = (f32x2){qq, qq};
        e0[q] = 3.4e38f; e1[q] = 3.4e38f; e2[q] = 3.4e38f;
    }

    const f32x2 zero2 = (f32x2){0.0f, 0.0f};
#pragma unroll 4
    for (int s = 0; s < SCH; s += 2) {
        // uniform 8B loads -> adjacent SGPR pairs (compiler merges groups)
        f32x2 X  = *(const f32x2*)&px[s];
        f32x2 Y  = *(const f32x2*)&py[s];
        f32x2 Z  = *(const f32x2*)&pz[s];
        f32x2 Wv = *(const f32x2*)&pw[s];
#pragma unroll
        for (int q = 0; q < QPT; ++q) {
            f32x2 cr = (qx2[q]*X + qy2[q]*Y) + qz2[q]*Z;   // == -2*dot, pk ops
            f32x2 dd = (qq2[q] + cr) + Wv;
            dd = __builtin_elementwise_max(dd, zero2);     // pk_max, == fmaxf/lane
            e2[q] = __builtin_amdgcn_fmed3f(e1[q], dd.x, e2[q]);
            e1[q] = __builtin_amdgcn_fmed3f(e0[q], dd.x, e1[q]);
            e0[q] = fminf(e0[q], dd.x);
            e2[q] = __builtin_amdgcn_fmed3f(e1[q], dd.y, e2[q]);
            e1[q] = __builtin_amdgcn_fmed3f(e0[q], dd.y, e1[q]);
            e0[q] = fminf(e0[q], dd.y);
        }
    }

#pragma unroll
    for (int q = 0; q < QPT; ++q) {
        int n = qc * (256 * QPT) + q * 256 + threadIdx.x;
        size_t m = (size_t)b * NN + n;
        size_t col = (size_t)sc * 3;
        pdist[(col+0)*MTOT + m] = e0[q];
        pdist[(col+1)*MTOT + m] = e1[q];
        pdist[(col+2)*MTOT + m] = e2[q];
    }
}

// ---------------------------------------------------------------------------
// 3-NN pass 2: merge chunk value-triples (ascending chunk order, strict '<').
// ---------------------------------------------------------------------------
__global__ __launch_bounds__(256) void knn3_merge_kernel(
    const float* __restrict__ pdist,
    float* __restrict__ w_out, float4* __restrict__ dmeta)
{
#pragma clang fp contract(off)
    int m = blockIdx.x * 256 + threadIdx.x;
    float d0 = 3.4e38f, d1 = 3.4e38f, d2 = 3.4e38f;
    int ch0 = 0, ch1 = 0, ch2 = 0;
#pragma unroll
    for (int c = 0; c < NCH; ++c) {
#pragma unroll
        for (int j = 0; j < 3; ++j) {
            float d = pdist[(size_t)(c*3+j)*MTOT + m];
            bool c0 = d < d0, c1 = d < d1, c2 = d < d2;
            d2 = c1 ? d1 : (c2 ? d : d2);  ch2 = c1 ? ch1 : (c2 ? c : ch2);
            d1 = c0 ? d0 : (c1 ? d : d1);  ch1 = c0 ? ch0 : (c1 ? c : ch1);
            d0 = c0 ? d : d0;              ch0 = c0 ? c : ch0;
        }
    }
    float r0 = 1.0f / (d0 + 1e-8f);
    float r1 = 1.0f / (d1 + 1e-8f);
    float r2 = 1.0f / (d2 + 1e-8f);
    float inv = 1.0f / ((r0 + r1) + r2);
    w_out[m*3+0] = r0 * inv;
    w_out[m*3+1] = r1 * inv;
    w_out[m*3+2] = r2 * inv;
    int k1 = (ch1 == ch0 && d1 == d0) ? 1 : 0;
    int k2 = ((ch2 == ch0 && d2 == d0) ? 1 : 0) + ((ch2 == ch1 && d2 == d1) ? 1 : 0);
    unsigned meta = (unsigned)ch0 | ((unsigned)ch1 << 4) | ((unsigned)ch2 << 8)
                  | ((unsigned)k1 << 12) | ((unsigned)k2 << 14);
    dmeta[m] = make_float4(d0, d1, d2, __uint_as_float(meta));
}

// ---------------------------------------------------------------------------
// 3-NN pass 3: index rescan. One WAVE per query; ballot/ffs rank extraction
// reproduces lax.top_k's stable ordering exactly.
// ---------------------------------------------------------------------------
__global__ __launch_bounds__(256) void knn3_rescan_kernel(
    const float* __restrict__ xyz1, const float4* __restrict__ packed,
    const float4* __restrict__ dmeta, int* __restrict__ idx_out)
{
#pragma clang fp contract(off)
    const int lane = threadIdx.x & 63;
    const int m = blockIdx.x * 4 + (threadIdx.x >> 6);
    const int b = m / NN;
    float4 dm = dmeta[m];
    const float d0 = dm.x, d1 = dm.y, d2 = dm.z;
    const unsigned meta = __float_as_uint(dm.w);
    const int ch0 = meta & 15, ch1 = (meta >> 4) & 15, ch2 = (meta >> 8) & 15;
    int r0 = 0, r1 = (meta >> 12) & 3, r2 = (meta >> 14) & 3;
    const float qx = xyz1[(size_t)m*3+0];
    const float qy = xyz1[(size_t)m*3+1];
    const float qz = xyz1[(size_t)m*3+2];
    const float qq = (qx*qx + qy*qy) + qz*qz;
    int i0 = 0, i1 = 0, i2 = 0;
    bool f0 = false, f1 = false, f2 = false;

    const float4* pb = packed + (size_t)b * SS;
#pragma unroll 1
    for (int pass = 0; pass < 3; ++pass) {
        int c = (pass == 0) ? ch0 : ((pass == 1) ? ch1 : ch2);
        if (pass == 1 && c == ch0) continue;
        if (pass == 2 && (c == ch0 || c == ch1)) continue;
#pragma unroll 1
        for (int it = 0; it < SCH/64; ++it) {
            float4 p = pb[c*SCH + it*64 + lane];
            float cr = (qx*p.x + qy*p.y) + qz*p.z;     // identical assoc to pass1
            float d = (qq + cr) + p.w;
            d = fmaxf(d, 0.0f);
            if (!f0 && c == ch0) {
                unsigned long long mk = __ballot(d == d0);
                int pc = __popcll(mk);
                if (r0 < pc) {
                    for (int t = 0; t < r0; ++t) mk &= (mk - 1ull);
                    i0 = c*SCH + it*64 + (__ffsll((long long)mk) - 1); f0 = true;
                } else r0 -= pc;
            }
            if (!f1 && c == ch1) {
                unsigned long long mk = __ballot(d == d1);
                int pc = __popcll(mk);
                if (r1 < pc) {
                    for (int t = 0; t < r1; ++t) mk &= (mk - 1ull);
                    i1 = c*SCH + it*64 + (__ffsll((long long)mk) - 1); f1 = true;
                } else r1 -= pc;
            }
            if (!f2 && c == ch2) {
                unsigned long long mk = __ballot(d == d2);
                int pc = __popcll(mk);
                if (r2 < pc) {
                    for (int t = 0; t < r2; ++t) mk &= (mk - 1ull);
                    i2 = c*SCH + it*64 + (__ffsll((long long)mk) - 1); f2 = true;
                } else r2 -= pc;
            }
            if ((f0 || c != ch0) && (f1 || c != ch1) && (f2 || c != ch2)) break;
        }
    }
    if (lane == 0) {
        idx_out[m*3+0] = b * SS + i0;
        idx_out[m*3+1] = b * SS + i1;
        idx_out[m*3+2] = b * SS + i2;
    }
}

// ---------------------------------------------------------------------------
// fp16 MFMA GEMM, LDS double-buffered, ONE barrier per k-iter (R5 structure --
// R6's no-LDS variant doubled FETCH+WRITE and regressed 2x; reverted).
// C[M x N] = op(A[M x K]) @ W[N x K]^T (+ bias).
// R11: 1D grid + XCD-chunked swizzle (gather slice per XCD fits its L2).
// R12: FUSE_STATS -> coalesced per-block partials (no atomics); NT f16 out.
// R14: launch_bounds (256,5); FUSE_INTERP -> cooperative wide-load gather
// via reused LDS (R5 had 50M scalar 2B gathers, latency-bound).
// ---------------------------------------------------------------------------
template<int K, typename AT, typename OT, bool BN_A, bool FUSE_INTERP, bool FUSE_STATS, bool NT>
__global__ __launch_bounds__(256, 5) void gemm_mfma_kernel(
    const AT* __restrict__ A, int lda,
    const _Float16* __restrict__ W, int ldw,
    OT* __restrict__ C, int ldc, int nxblk,
    const float* __restrict__ bias,
    const float* __restrict__ scaleA, const float* __restrict__ shiftA,
    const _Float16* __restrict__ P2, const int* __restrict__ idx3, const float* __restrict__ w3,
    float2* __restrict__ pstatO)
{
    __shared__ __align__(16) char smem[30720];
    _Float16 (*Ash)[64 * LPAD]  = (_Float16(*)[64 * LPAD])smem;            // 2 x 5120 B
    _Float16 (*Bsh)[128 * LPAD] = (_Float16(*)[128 * LPAD])(smem + 10240); // 2 x 10240 B

    const int tid = threadIdx.x;
    const int nwg = gridDim.x;
    const int chunk = nwg >> 3;                 // all grids divisible by 8
    const int logical = (blockIdx.x & 7) * chunk + (blockIdx.x >> 3);
    const int m0 = (logical % nxblk) * 64;
    const int n0 = (logical / nxblk) * 128;
    const int wave = tid >> 6, lane = tid & 63;
    const int ln = lane & 15, q4 = lane >> 4;
    const int wm = wave & 1, wn = wave >> 1;

    const int ar = tid >> 2, ak = (tid & 3) * 8;   // A staging: 64 rows x 32k
    const int br = tid >> 1, bk = (tid & 1) * 16;  // B staging: 128 rows x 32k

    f32x4 acc[2][4] = {};

    float  avF[8];      // used when AT == float
    f16x8  avH;         // used when AT == _Float16
    f16x8  bvA[2];

    {   // prologue prefetch k0 = 0
        if constexpr (__is_same(AT, float)) {
            const float* ap = A + (size_t)(m0 + ar) * lda + ak;
            *(float4*)&avF[0] = *(const float4*)ap;
            *(float4*)&avF[4] = *(const float4*)(ap + 4);
        } else {
            avH = *(const f16x8*)(A + (size_t)(m0 + ar) * lda + ak);
        }
        const _Float16* bp = W + (size_t)(n0 + br) * ldw + bk;
        bvA[0] = *(const f16x8*)bp;
        bvA[1] = *(const f16x8*)(bp + 8);
    }

    for (int k0 = 0; k0 < K; k0 += 32) {
        const int buf = (k0 >> 5) & 1;

        // ---- transform + store staged regs to LDS[buf] ----
        {
            float av[8];
            if constexpr (__is_same(AT, float)) {
#pragma unroll
                for (int i = 0; i < 8; ++i) av[i] = avF[i];
            } else {
#pragma unroll
                for (int i = 0; i < 8; ++i) av[i] = (float)avH[i];
            }
            if (BN_A) {
#pragma unroll
                for (int i = 0; i < 8; ++i) {
                    float sc = scaleA[k0 + ak + i];
                    float sh = shiftA[k0 + ak + i];
                    av[i] = fmaxf(av[i] * sc + sh, 0.0f);
                }
            }
            f16x8 vh;
#pragma unroll
            for (int i = 0; i < 8; ++i) vh[i] = (_Float16)av[i];
            *(f16x8*)&Ash[buf][ar * LPAD + ak] = vh;
            *(f16x8*)&Bsh[buf][br * LPAD + bk]     = bvA[0];
            *(f16x8*)&Bsh[buf][br * LPAD + bk + 8] = bvA[1];
        }
        __syncthreads();    // single barrier: writers of buf done; dbuf makes it safe

        // ---- issue next chunk's global loads (overlap with MFMA below) ----
        if (k0 + 32 < K) {
            if constexpr (__is_same(AT, float)) {
                const float* ap = A + (size_t)(m0 + ar) * lda + (k0 + 32) + ak;
                *(float4*)&avF[0] = *(const float4*)ap;
                *(float4*)&avF[4] = *(const float4*)(ap + 4);
            } else {
                avH = *(const f16x8*)(A + (size_t)(m0 + ar) * lda + (k0 + 32) + ak);
            }
            const _Float16* bp = W + (size_t)(n0 + br) * ldw + (k0 + 32) + bk;
            bvA[0] = *(const f16x8*)bp;
            bvA[1] = *(const f16x8*)(bp + 8);
        }

        // ---- fragments + MFMA ----
        f16x8 af[2];
#pragma unroll
        for (int mi = 0; mi < 2; ++mi) {
            int arow = wm * 32 + mi * 16 + ln;
            af[mi] = *(const f16x8*)&Ash[buf][arow * LPAD + q4 * 8];
        }
        f16x8 bf[4];
#pragma unroll
        for (int ni = 0; ni < 4; ++ni) {
            int brow = wn * 64 + ni * 16 + ln;
            bf[ni] = *(const f16x8*)&Bsh[buf][brow * LPAD + q4 * 8];
        }
#pragma unroll
        for (int mi = 0; mi < 2; ++mi)
#pragma unroll
            for (int ni = 0; ni < 4; ++ni)
                acc[mi][ni] = __builtin_amdgcn_mfma_f32_16x16x32_f16(af[mi], bf[ni], acc[mi][ni], 0, 0, 0);
    }

    // ---- epilogue ----  C/D layout: col = ln, row = q4*4 + r  (m89/m91)
    if (FUSE_INTERP) {
        // Two-phase cooperative gather (by wm half). All threads produce;
        // wm==h waves consume. G is f32 [32][GSTRIDE] over the staging LDS.
        __syncthreads();                       // k-loop LDS reads complete
        float* G = (float*)smem;
        const int rg = tid >> 3;               // 0..31: row within half
        const int cg = tid & 7;                // 0..7: 16-col group
#pragma unroll 1
        for (int h = 0; h < 2; ++h) {
            int row_g = m0 + h * 32 + rg;
            const int*   ip = idx3 + (size_t)row_g * 3;
            const float* wp = w3   + (size_t)row_g * 3;
            int   ia = ip[0], ib = ip[1], ic = ip[2];
            float wa = wp[0], wb = wp[1], wc = wp[2];
            const _Float16* pa = P2 + (size_t)ia * C1 + n0 + cg * 16;
            const _Float16* pb = P2 + (size_t)ib * C1 + n0 + cg * 16;
            const _Float16* pc = P2 + (size_t)ic * C1 + n0 + cg * 16;
            f16x8 va0 = *(const f16x8*)pa, va1 = *(const f16x8*)(pa + 8);
            f16x8 vb0 = *(const f16x8*)pb, vb1 = *(const f16x8*)(pb + 8);
            f16x8 vc0 = *(const f16x8*)pc, vc1 = *(const f16x8*)(pc + 8);
            float g[16];
#pragma unroll
            for (int i = 0; i < 8; ++i) {
                g[i]     = wa * (float)va0[i] + wb * (float)vb0[i] + wc * (float)vc0[i];
                g[8 + i] = wa * (float)va1[i] + wb * (float)vb1[i] + wc * (float)vc1[i];
            }
#pragma unroll
            for (int i = 0; i < 4; ++i) {
                float4 t4 = make_float4(g[i*4+0], g[i*4+1], g[i*4+2], g[i*4+3]);
                *(float4*)&G[rg * GSTRIDE + cg * 16 + i * 4] = t4;
            }
            __syncthreads();                   // G[h] ready
            if (wm == h) {
#pragma unroll
                for (int mi = 0; mi < 2; ++mi)
#pragma unroll
                    for (int r = 0; r < 4; ++r) {
                        int row_l = mi * 16 + q4 * 4 + r;
#pragma unroll
                        for (int ni = 0; ni < 4; ++ni)
                            acc[mi][ni][r] += G[row_l * GSTRIDE + wn * 64 + ni * 16 + ln];
                    }
            }
            __syncthreads();                   // consumers done before next fill
        }
    }

#pragma unroll
    for (int ni = 0; ni < 4; ++ni) {
        int col = n0 + wn * 64 + ni * 16 + ln;
        float vb = bias ? bias[col] : 0.0f;
        float s = 0.0f, s2 = 0.0f;
#pragma unroll
        for (int mi = 0; mi < 2; ++mi) {
#pragma unroll
            for (int r = 0; r < 4; ++r) {
                int row_g = m0 + wm * 32 + mi * 16 + q4 * 4 + r;
                float v = acc[mi][ni][r] + vb;
                if constexpr (NT) {
                    __builtin_nontemporal_store((OT)v, &C[(size_t)row_g * ldc + col]);
                } else {
                    C[(size_t)row_g * ldc + col] = (OT)v;
                }
                s += v; s2 += v * v;
            }
        }
        if (FUSE_STATS) {
            s  += __shfl_xor(s, 16);  s  += __shfl_xor(s, 32);
            s2 += __shfl_xor(s2, 16); s2 += __shfl_xor(s2, 32);
            if (q4 == 0) {
                // coalesced partial: slot layout [logical][wave][ni][ln]
                pstatO[(size_t)logical * 256 + wave * 64 + ni * 16 + ln] =
                    make_float2(s, s2);
            }
        }
    }
}

// ---------------------------------------------------------------------------
// Fold per-block stat partials into sum/sq. Slot layout matches the GEMM
// writer: t = wave*64 + ni*16 + ln; col = half*128 + (wave>>1)*64 + ni*16+ln.
// ---------------------------------------------------------------------------
__global__ __launch_bounds__(256) void stats_reduce_kernel(
    const float2* __restrict__ pstat, int nxblk, int mper,
    float* __restrict__ sumO, float* __restrict__ sqO)
{
    const int bper = nxblk / mper;
    const int half = blockIdx.x / bper;
    const int mb0  = (blockIdx.x % bper) * mper;
    const int t = threadIdx.x;
    float s = 0.0f, s2 = 0.0f;
    for (int mb = mb0; mb < mb0 + mper; ++mb) {
        float2 v = pstat[(size_t)(half * nxblk + mb) * 256 + t];
        s += v.x; s2 += v.y;
    }
    const int wave = t >> 6, wn = wave >> 1, ni = (t >> 4) & 3, ln = t & 15;
    const int col = half * 128 + wn * 64 + ni * 16 + ln;
    atomicAdd(&sumO[col], s);
    atomicAdd(&sqO[col], s2);
}

// ---------------------------------------------------------------------------
__global__ void finalize_kernel(
    const float* __restrict__ sum, const float* __restrict__ sumsq,
    const float* __restrict__ g, const float* __restrict__ beta,
    int M, int C, float* __restrict__ scale, float* __restrict__ shift)
{
    int c = threadIdx.x;
    if (c >= C) return;
    float invM = 1.0f / (float)M;
    float mean = sum[c] * invM;
    float var = fmaxf(sumsq[c] * invM - mean * mean, 0.0f);
    float rstd = 1.0f / sqrtf(var + 1e-5f);
    float sc = g[c] * rstd;
    scale[c] = sc;
    shift[c] = beta[c] - mean * sc;
}

__global__ __launch_bounds__(256) void bnrelu_kernel(
    float* __restrict__ X, int total, int C,
    const float* __restrict__ scale, const float* __restrict__ shift)
{
    int i = blockIdx.x * 256 + threadIdx.x;
    if (i >= total) return;
    int c = i & (C - 1);
    X[i] = fmaxf(X[i] * scale[c] + shift[c], 0.0f);
}

// ---------------------------------------------------------------------------
extern "C" void kernel_launch(void* const* d_in, const int* in_sizes, int n_in,
                              void* d_out, int out_size, void* d_ws, size_t ws_size,
                              hipStream_t stream) {
    const float* xyz1    = (const float*)d_in[0];
    const float* xyz2    = (const float*)d_in[1];
    const float* points1 = (const float*)d_in[2];
    const float* points2 = (const float*)d_in[3];
    const float* W1      = (const float*)d_in[4];
    const float* b1      = (const float*)d_in[5];
    const float* g1      = (const float*)d_in[6];
    const float* beta1   = (const float*)d_in[7];
    const float* W2      = (const float*)d_in[8];
    const float* b2      = (const float*)d_in[9];
    const float* g2      = (const float*)d_in[10];
    const float* beta2   = (const float*)d_in[11];
    float* out = (float*)d_out;

    // ws layout (byte offsets, 16B-aligned)
    char* ws = (char*)d_ws;
    size_t off = 0;
    int*   idx = (int*)(ws + off);            off += (size_t)MTOT*3*4;
    float* w   = (float*)(ws + off);          off += (size_t)MTOT*3*4;
    _Float16* P2h = (_Float16*)(ws + off);    off += (size_t)BB*SS*C1*2;    // 8 MB
    _Float16* y1h = (_Float16*)(ws + off);    off += (size_t)MTOT*C1*2;     // 32 MB
    float* stats = (float*)(ws + off);        off += 2048*4;
    float* sum1 = stats;            // 256
    float* sq1  = stats + 256;      // 256
    float* sum2 = stats + 512;      // 128
    float* sq2  = stats + 640;      // 128
    float* scale1 = stats + 768;    // 256
    float* shift1 = stats + 1024;   // 256
    float* scale2 = stats + 1280;   // 128
    float* shift2 = stats + 1408;   // 128
    float4* packed = (float4*)(ws + off);     off += (size_t)BB*SS*16;      // 1 MB
    float* pxp = (float*)(ws + off);          off += (size_t)BB*SS*4;       // 256 KB
    float* pyp = (float*)(ws + off);          off += (size_t)BB*SS*4;
    float* pzp = (float*)(ws + off);          off += (size_t)BB*SS*4;
    float* pwp = (float*)(ws + off);          off += (size_t)BB*SS*4;
    _Float16* W1c = (_Float16*)(ws + off);    off += (size_t)C1*(D1+D2)*2;
    _Float16* W2c = (_Float16*)(ws + off);    off += (size_t)C2*C1*2;
    off = (off + 255) & ~(size_t)255;
    float2* pstat = (float2*)(ws + off);      off += (size_t)2048*256*8;    // 4 MB
    // knn partials alias the y1h region (32 MB; y1h written later in stream
    // order): pdist = NCH*3*MTOT floats (12.6 MB) at +0, dmeta (1 MB) at +20MB.
    float*  pdist = (float*)y1h;
    float4* dmeta = (float4*)((char*)y1h + (size_t)20*1024*1024);

    hipMemsetAsync(stats, 0, 768 * sizeof(float), stream);

    pack_kernel<<<(BB*SS)/256, 256, 0, stream>>>(xyz2, packed, pxp, pyp, pzp, pwp);
    wcvt_kernel<<<(C1*(D1+D2))/256, 256, 0, stream>>>(W1, W2, W1c, W2c);

    knn3_partial_kernel<<<BB * (NN/(256*QPT)) * NCH, 256, 0, stream>>>(
        xyz1, pxp, pyp, pzp, pwp, pdist);
    knn3_merge_kernel<<<MTOT/256, 256, 0, stream>>>(pdist, w, dmeta);
    knn3_rescan_kernel<<<MTOT/4, 256, 0, stream>>>(xyz1, packed, dmeta, idx);

    // P2 = points2 @ W1[:,128:]^T   [B*S x 256], K=256, f16 out
    gemm_mfma_kernel<256, float, _Float16, false, false, false, false>
        <<<256*2, 256, 0, stream>>>(
        points2, D2, W1c + D1, D1 + D2, P2h, C1, 256,
        nullptr, nullptr, nullptr, nullptr, nullptr, nullptr, nullptr);

    // y1 = points1 @ W1[:,:128]^T + b1 + interp;  f16 NT out; partial stats
    gemm_mfma_kernel<128, float, _Float16, false, true, true, true>
        <<<1024*2, 256, 0, stream>>>(
        points1, D1, W1c, D1 + D2, y1h, C1, 1024,
        b1, nullptr, nullptr, P2h, idx, w, pstat);

    stats_reduce_kernel<<<32, 256, 0, stream>>>(pstat, 1024, 64, sum1, sq1);
    finalize_kernel<<<1, 256, 0, stream>>>(sum1, sq1, g1, beta1, MTOT, C1, scale1, shift1);

    // out = relu(bn1(y1)) @ W2^T + b2;  fp32 out; partial stats
    gemm_mfma_kernel<256, _Float16, float, true, false, true, false>
        <<<1024*1, 256, 0, stream>>>(
        y1h, C1, W2c, C1, out, C2, 1024,
        b2, scale1, shift1, nullptr, nullptr, nullptr, pstat);

    stats_reduce_kernel<<<16, 256, 0, stream>>>(pstat, 1024, 64, sum2, sq2);
    finalize_kernel<<<1, 128, 0, stream>>>(sum2, sq2, g2, beta2, MTOT, C2, scale2, shift2);
    bnrelu_kernel<<<(MTOT*C2)/256, 256, 0, stream>>>(out, MTOT*C2, C2, scale2, shift2);
}

// Round 12
// 347.046 us; speedup vs baseline: 1.0507x; 1.0507x over previous
//
#include <hip/hip_runtime.h>
#include <hip/hip_bf16.h>
#include <math.h>

// Problem constants (fixed by setup_inputs)
#define BB 4
#define NN 16384
#define SS 4096
#define D1 128
#define D2 256
#define C1 256   // mlp[0]
#define C2 128   // mlp[1]
#define MTOT (BB*NN)   // 65536

// knn decomposition. Pass1 distance-only; indices recovered by rescan
// (ballot first-occurrence == lax.top_k stable tie rule).
// R16: candidates wave-uniform -> s_load scalar stream.
// R19 (this round): HYBRID streams. R10/R11 post-mortem: v_pk_f32 is
// double-width (4cyc/wave64) -> pk cut insts but not cycles; kernel is
// VALU+wait bound at ~53% issue efficiency (floor ~37us, measured 70).
// Split candidates 50/50: [0,128) via s_load (lgkmcnt), [128,256) via
// uniform-address vector global_load (vmcnt, L1-broadcast) -- two
// independent wait counters, latencies hide each other. Value min-network
// is order-insensitive -> interleave is exact. QPT back to 2 (R11's 4
// regressed: occupancy halved).
#define QPT 2              // queries per thread
#define SCH 256            // candidates per chunk (4KB, L1/L2-resident)
#define NCH (SS/SCH)       // 16 chunks

typedef _Float16 f16x8 __attribute__((ext_vector_type(8)));
typedef float f32x4  __attribute__((ext_vector_type(4)));
typedef float f32x2  __attribute__((ext_vector_type(2)));

#define LPAD 40            // LDS row stride in fp16 elems (80B, 16B-aligned)
#define GSTRIDE 132        // f32 interp buffer row stride (528B: 16B-aligned, <=2-way banks)

// ---------------------------------------------------------------------------
// Pack xyz2 into {-2x, -2y, -2z, ||p||^2}: AoS float4 (vector stream +
// rescan) AND SoA planes (scalar stream).
// Scaling by -2 is EXACT (power of two commutes with IEEE rounding), so
// d = (qq + cr2) + pw is bit-identical to the reference association
// d = (qq - 2*cr) + pw.
// ---------------------------------------------------------------------------
__global__ __launch_bounds__(256) void pack_kernel(
    const float* __restrict__ xyz2, float4* __restrict__ packed,
    float* __restrict__ pxp, float* __restrict__ pyp,
    float* __restrict__ pzp, float* __restrict__ pwp)
{
#pragma clang fp contract(off)
    int s = blockIdx.x * 256 + threadIdx.x;
    float px = xyz2[s*3+0], py = xyz2[s*3+1], pz = xyz2[s*3+2];
    float pp = (px*px + py*py) + pz*pz;
    float ax = px * -2.0f, ay = py * -2.0f, az = pz * -2.0f;
    packed[s] = make_float4(ax, ay, az, pp);
    pxp[s] = ax; pyp[s] = ay; pzp[s] = az; pwp[s] = pp;
}

// ---------------------------------------------------------------------------
// Convert W1, W2 to fp16 (RNE) once.
// ---------------------------------------------------------------------------
__global__ __launch_bounds__(256) void wcvt_kernel(
    const float* __restrict__ W1, const float* __restrict__ W2,
    _Float16* __restrict__ W1c, _Float16* __restrict__ W2c)
{
    int i = blockIdx.x * 256 + threadIdx.x;
    if (i < C1 * (D1 + D2)) W1c[i] = (_Float16)W1[i];
    if (i < C2 * C1)        W2c[i] = (_Float16)W2[i];
}

// ---------------------------------------------------------------------------
// 3-NN pass 1 (DISTANCE-ONLY, hybrid scalar+vector candidate streams):
// exact fp32 distances (contract off, reference association), min/med3
// value network (order-insensitive). Indices recovered in rescan.
// HARD CONSTRAINT: never approximate the distance or the comparison.
// ---------------------------------------------------------------------------
__global__ __launch_bounds__(256, 8) void knn3_partial_kernel(
    const float* __restrict__ xyz1, const float4* __restrict__ packed,
    const float* __restrict__ pxp, const float* __restrict__ pyp,
    const float* __restrict__ pzp, const float* __restrict__ pwp,
    float* __restrict__ pdist)
{
#pragma clang fp contract(off)
    const int qblocks = NN / (256 * QPT);            // 32
    const int b  = blockIdx.x / (qblocks * NCH);
    const int r  = blockIdx.x % (qblocks * NCH);
    const int qc = r / NCH;
    const int sc = r % NCH;

    // scalar stream: candidates [0, SCH/2) via SoA planes (s_load, lgkmcnt)
    const float* __restrict__ px = pxp + (size_t)b * SS + sc * SCH;
    const float* __restrict__ py = pyp + (size_t)b * SS + sc * SCH;
    const float* __restrict__ pz = pzp + (size_t)b * SS + sc * SCH;
    const float* __restrict__ pw = pwp + (size_t)b * SS + sc * SCH;
    // vector stream: candidates [SCH/2, SCH) via AoS (global_load, vmcnt).
    // divergence-opaque zero forces the VECTOR path (compiler cannot prove
    // the address uniform -> no scalarization to s_load).
    const int lzero = __shfl(0, 0);
    const float4* __restrict__ pv =
        packed + (size_t)b * SS + sc * SCH + SCH/2 + lzero;

    f32x2 qx2[QPT], qy2[QPT], qz2[QPT], qq2[QPT];
    float e0[QPT], e1[QPT], e2[QPT];
#pragma unroll
    for (int q = 0; q < QPT; ++q) {
        int n = qc * (256 * QPT) + q * 256 + threadIdx.x;
        size_t m = (size_t)b * NN + n;
        float qx = xyz1[m*3+0], qy = xyz1[m*3+1], qz = xyz1[m*3+2];
        float qq = (qx*qx + qy*qy) + qz*qz;
        qx2[q] = (f32x2){qx, qx}; qy2[q] = (f32x2){qy, qy};
        qz2[q] = (f32x2){qz, qz}; qq2[q] = (f32x2){qq, qq};
        e0[q] = 3.4e38f; e1[q] = 3.4e38f; e2[q] = 3.4e38f;
    }

    const f32x2 zero2 = (f32x2){0.0f, 0.0f};
#pragma unroll 2
    for (int s = 0; s < SCH/2; s += 2) {
        // scalar stream pair (s_load -> SGPR pairs)
        f32x2 X  = *(const f32x2*)&px[s];
        f32x2 Y  = *(const f32x2*)&py[s];
        f32x2 Z  = *(const f32x2*)&pz[s];
        f32x2 Wv = *(const f32x2*)&pw[s];
        // vector stream pair (global_load_dwordx4, L1 broadcast)
        float4 pA = pv[s];
        float4 pB = pv[s+1];
#pragma unroll
        for (int q = 0; q < QPT; ++q) {
            // --- scalar-stream candidates s, s+1 ---
            f32x2 cr = (qx2[q]*X + qy2[q]*Y) + qz2[q]*Z;   // == -2*dot
            f32x2 dd = (qq2[q] + cr) + Wv;
            dd = __builtin_elementwise_max(dd, zero2);
            e2[q] = __builtin_amdgcn_fmed3f(e1[q], dd.x, e2[q]);
            e1[q] = __builtin_amdgcn_fmed3f(e0[q], dd.x, e1[q]);
            e0[q] = fminf(e0[q], dd.x);
            e2[q] = __builtin_amdgcn_fmed3f(e1[q], dd.y, e2[q]);
            e1[q] = __builtin_amdgcn_fmed3f(e0[q], dd.y, e1[q]);
            e0[q] = fminf(e0[q], dd.y);
            // --- vector-stream candidates SCH/2+s, SCH/2+s+1 ---
            float qx = qx2[q].x, qy = qy2[q].x, qz = qz2[q].x, qq = qq2[q].x;
            float crA = (qx*pA.x + qy*pA.y) + qz*pA.z;
            float dA = (qq + crA) + pA.w;
            dA = fmaxf(dA, 0.0f);
            e2[q] = __builtin_amdgcn_fmed3f(e1[q], dA, e2[q]);
            e1[q] = __builtin_amdgcn_fmed3f(e0[q], dA, e1[q]);
            e0[q] = fminf(e0[q], dA);
            float crB = (qx*pB.x + qy*pB.y) + qz*pB.z;
            float dB = (qq + crB) + pB.w;
            dB = fmaxf(dB, 0.0f);
            e2[q] = __builtin_amdgcn_fmed3f(e1[q], dB, e2[q]);
            e1[q] = __builtin_amdgcn_fmed3f(e0[q], dB, e1[q]);
            e0[q] = fminf(e0[q], dB);
        }
    }

#pragma unroll
    for (int q = 0; q < QPT; ++q) {
        int n = qc * (256 * QPT) + q * 256 + threadIdx.x;
        size_t m = (size_t)b * NN + n;
        size_t col = (size_t)sc * 3;
        pdist[(col+0)*MTOT + m] = e0[q];
        pdist[(col+1)*MTOT + m] = e1[q];
        pdist[(col+2)*MTOT + m] = e2[q];
    }
}

// ---------------------------------------------------------------------------
// 3-NN pass 2: merge chunk value-triples (ascending chunk order, strict '<').
// ---------------------------------------------------------------------------
__global__ __launch_bounds__(256) void knn3_merge_kernel(
    const float* __restrict__ pdist,
    float* __restrict__ w_out, float4* __restrict__ dmeta)
{
#pragma clang fp contract(off)
    int m = blockIdx.x * 256 + threadIdx.x;
    float d0 = 3.4e38f, d1 = 3.4e38f, d2 = 3.4e38f;
    int ch0 = 0, ch1 = 0, ch2 = 0;
#pragma unroll
    for (int c = 0; c < NCH; ++c) {
#pragma unroll
        for (int j = 0; j < 3; ++j) {
            float d = pdist[(size_t)(c*3+j)*MTOT + m];
            bool c0 = d < d0, c1 = d < d1, c2 = d < d2;
            d2 = c1 ? d1 : (c2 ? d : d2);  ch2 = c1 ? ch1 : (c2 ? c : ch2);
            d1 = c0 ? d0 : (c1 ? d : d1);  ch1 = c0 ? ch0 : (c1 ? c : ch1);
            d0 = c0 ? d : d0;              ch0 = c0 ? c : ch0;
        }
    }
    float r0 = 1.0f / (d0 + 1e-8f);
    float r1 = 1.0f / (d1 + 1e-8f);
    float r2 = 1.0f / (d2 + 1e-8f);
    float inv = 1.0f / ((r0 + r1) + r2);
    w_out[m*3+0] = r0 * inv;
    w_out[m*3+1] = r1 * inv;
    w_out[m*3+2] = r2 * inv;
    int k1 = (ch1 == ch0 && d1 == d0) ? 1 : 0;
    int k2 = ((ch2 == ch0 && d2 == d0) ? 1 : 0) + ((ch2 == ch1 && d2 == d1) ? 1 : 0);
    unsigned meta = (unsigned)ch0 | ((unsigned)ch1 << 4) | ((unsigned)ch2 << 8)
                  | ((unsigned)k1 << 12) | ((unsigned)k2 << 14);
    dmeta[m] = make_float4(d0, d1, d2, __uint_as_float(meta));
}

// ---------------------------------------------------------------------------
// 3-NN pass 3: index rescan. One WAVE per query; ballot/ffs rank extraction
// reproduces lax.top_k's stable ordering exactly.
// ---------------------------------------------------------------------------
__global__ __launch_bounds__(256) void knn3_rescan_kernel(
    const float* __restrict__ xyz1, const float4* __restrict__ packed,
    const float4* __restrict__ dmeta, int* __restrict__ idx_out)
{
#pragma clang fp contract(off)
    const int lane = threadIdx.x & 63;
    const int m = blockIdx.x * 4 + (threadIdx.x >> 6);
    const int b = m / NN;
    float4 dm = dmeta[m];
    const float d0 = dm.x, d1 = dm.y, d2 = dm.z;
    const unsigned meta = __float_as_uint(dm.w);
    const int ch0 = meta & 15, ch1 = (meta >> 4) & 15, ch2 = (meta >> 8) & 15;
    int r0 = 0, r1 = (meta >> 12) & 3, r2 = (meta >> 14) & 3;
    const float qx = xyz1[(size_t)m*3+0];
    const float qy = xyz1[(size_t)m*3+1];
    const float qz = xyz1[(size_t)m*3+2];
    const float qq = (qx*qx + qy*qy) + qz*qz;
    int i0 = 0, i1 = 0, i2 = 0;
    bool f0 = false, f1 = false, f2 = false;

    const float4* pb = packed + (size_t)b * SS;
#pragma unroll 1
    for (int pass = 0; pass < 3; ++pass) {
        int c = (pass == 0) ? ch0 : ((pass == 1) ? ch1 : ch2);
        if (pass == 1 && c == ch0) continue;
        if (pass == 2 && (c == ch0 || c == ch1)) continue;
#pragma unroll 1
        for (int it = 0; it < SCH/64; ++it) {
            float4 p = pb[c*SCH + it*64 + lane];
            float cr = (qx*p.x + qy*p.y) + qz*p.z;     // identical assoc to pass1
            float d = (qq + cr) + p.w;
            d = fmaxf(d, 0.0f);
            if (!f0 && c == ch0) {
                unsigned long long mk = __ballot(d == d0);
                int pc = __popcll(mk);
                if (r0 < pc) {
                    for (int t = 0; t < r0; ++t) mk &= (mk - 1ull);
                    i0 = c*SCH + it*64 + (__ffsll((long long)mk) - 1); f0 = true;
                } else r0 -= pc;
            }
            if (!f1 && c == ch1) {
                unsigned long long mk = __ballot(d == d1);
                int pc = __popcll(mk);
                if (r1 < pc) {
                    for (int t = 0; t < r1; ++t) mk &= (mk - 1ull);
                    i1 = c*SCH + it*64 + (__ffsll((long long)mk) - 1); f1 = true;
                } else r1 -= pc;
            }
            if (!f2 && c == ch2) {
                unsigned long long mk = __ballot(d == d2);
                int pc = __popcll(mk);
                if (r2 < pc) {
                    for (int t = 0; t < r2; ++t) mk &= (mk - 1ull);
                    i2 = c*SCH + it*64 + (__ffsll((long long)mk) - 1); f2 = true;
                } else r2 -= pc;
            }
            if ((f0 || c != ch0) && (f1 || c != ch1) && (f2 || c != ch2)) break;
        }
    }
    if (lane == 0) {
        idx_out[m*3+0] = b * SS + i0;
        idx_out[m*3+1] = b * SS + i1;
        idx_out[m*3+2] = b * SS + i2;
    }
}

// ---------------------------------------------------------------------------
// fp16 MFMA GEMM, LDS double-buffered, ONE barrier per k-iter (R5 structure).
// R11: 1D grid + XCD-chunked swizzle. R12: FUSE_STATS -> coalesced per-block
// partials. R14: launch_bounds (256,5); FUSE_INTERP -> cooperative
// wide-load gather via reused LDS. R19: NT dropped (never delivered its
// predicted FETCH cut; y1h now rides L2 for GEMM3's reads).
// ---------------------------------------------------------------------------
template<int K, typename AT, typename OT, bool BN_A, bool FUSE_INTERP, bool FUSE_STATS, bool NT>
__global__ __launch_bounds__(256, 5) void gemm_mfma_kernel(
    const AT* __restrict__ A, int lda,
    const _Float16* __restrict__ W, int ldw,
    OT* __restrict__ C, int ldc, int nxblk,
    const float* __restrict__ bias,
    const float* __restrict__ scaleA, const float* __restrict__ shiftA,
    const _Float16* __restrict__ P2, const int* __restrict__ idx3, const float* __restrict__ w3,
    float2* __restrict__ pstatO)
{
    __shared__ __align__(16) char smem[30720];
    _Float16 (*Ash)[64 * LPAD]  = (_Float16(*)[64 * LPAD])smem;            // 2 x 5120 B
    _Float16 (*Bsh)[128 * LPAD] = (_Float16(*)[128 * LPAD])(smem + 10240); // 2 x 10240 B

    const int tid = threadIdx.x;
    const int nwg = gridDim.x;
    const int chunk = nwg >> 3;                 // all grids divisible by 8
    const int logical = (blockIdx.x & 7) * chunk + (blockIdx.x >> 3);
    const int m0 = (logical % nxblk) * 64;
    const int n0 = (logical / nxblk) * 128;
    const int wave = tid >> 6, lane = tid & 63;
    const int ln = lane & 15, q4 = lane >> 4;
    const int wm = wave & 1, wn = wave >> 1;

    const int ar = tid >> 2, ak = (tid & 3) * 8;   // A staging: 64 rows x 32k
    const int br = tid >> 1, bk = (tid & 1) * 16;  // B staging: 128 rows x 32k

    f32x4 acc[2][4] = {};

    float  avF[8];      // used when AT == float
    f16x8  avH;         // used when AT == _Float16
    f16x8  bvA[2];

    {   // prologue prefetch k0 = 0
        if constexpr (__is_same(AT, float)) {
            const float* ap = A + (size_t)(m0 + ar) * lda + ak;
            *(float4*)&avF[0] = *(const float4*)ap;
            *(float4*)&avF[4] = *(const float4*)(ap + 4);
        } else {
            avH = *(const f16x8*)(A + (size_t)(m0 + ar) * lda + ak);
        }
        const _Float16* bp = W + (size_t)(n0 + br) * ldw + bk;
        bvA[0] = *(const f16x8*)bp;
        bvA[1] = *(const f16x8*)(bp + 8);
    }

    for (int k0 = 0; k0 < K; k0 += 32) {
        const int buf = (k0 >> 5) & 1;

        // ---- transform + store staged regs to LDS[buf] ----
        {
            float av[8];
            if constexpr (__is_same(AT, float)) {
#pragma unroll
                for (int i = 0; i < 8; ++i) av[i] = avF[i];
            } else {
#pragma unroll
                for (int i = 0; i < 8; ++i) av[i] = (float)avH[i];
            }
            if (BN_A) {
#pragma unroll
                for (int i = 0; i < 8; ++i) {
                    float sc = scaleA[k0 + ak + i];
                    float sh = shiftA[k0 + ak + i];
                    av[i] = fmaxf(av[i] * sc + sh, 0.0f);
                }
            }
            f16x8 vh;
#pragma unroll
            for (int i = 0; i < 8; ++i) vh[i] = (_Float16)av[i];
            *(f16x8*)&Ash[buf][ar * LPAD + ak] = vh;
            *(f16x8*)&Bsh[buf][br * LPAD + bk]     = bvA[0];
            *(f16x8*)&Bsh[buf][br * LPAD + bk + 8] = bvA[1];
        }
        __syncthreads();    // single barrier: writers of buf done; dbuf makes it safe

        // ---- issue next chunk's global loads (overlap with MFMA below) ----
        if (k0 + 32 < K) {
            if constexpr (__is_same(AT, float)) {
                const float* ap = A + (size_t)(m0 + ar) * lda + (k0 + 32) + ak;
                *(float4*)&avF[0] = *(const float4*)ap;
                *(float4*)&avF[4] = *(const float4*)(ap + 4);
            } else {
                avH = *(const f16x8*)(A + (size_t)(m0 + ar) * lda + (k0 + 32) + ak);
            }
            const _Float16* bp = W + (size_t)(n0 + br) * ldw + (k0 + 32) + bk;
            bvA[0] = *(const f16x8*)bp;
            bvA[1] = *(const f16x8*)(bp + 8);
        }

        // ---- fragments + MFMA ----
        f16x8 af[2];
#pragma unroll
        for (int mi = 0; mi < 2; ++mi) {
            int arow = wm * 32 + mi * 16 + ln;
            af[mi] = *(const f16x8*)&Ash[buf][arow * LPAD + q4 * 8];
        }
        f16x8 bf[4];
#pragma unroll
        for (int ni = 0; ni < 4; ++ni) {
            int brow = wn * 64 + ni * 16 + ln;
            bf[ni] = *(const f16x8*)&Bsh[buf][brow * LPAD + q4 * 8];
        }
#pragma unroll
        for (int mi = 0; mi < 2; ++mi)
#pragma unroll
            for (int ni = 0; ni < 4; ++ni)
                acc[mi][ni] = __builtin_amdgcn_mfma_f32_16x16x32_f16(af[mi], bf[ni], acc[mi][ni], 0, 0, 0);
    }

    // ---- epilogue ----  C/D layout: col = ln, row = q4*4 + r  (m89/m91)
    if (FUSE_INTERP) {
        // Two-phase cooperative gather (by wm half). All threads produce;
        // wm==h waves consume. G is f32 [32][GSTRIDE] over the staging LDS.
        __syncthreads();                       // k-loop LDS reads complete
        float* G = (float*)smem;
        const int rg = tid >> 3;               // 0..31: row within half
        const int cg = tid & 7;                // 0..7: 16-col group
#pragma unroll 1
        for (int h = 0; h < 2; ++h) {
            int row_g = m0 + h * 32 + rg;
            const int*   ip = idx3 + (size_t)row_g * 3;
            const float* wp = w3   + (size_t)row_g * 3;
            int   ia = ip[0], ib = ip[1], ic = ip[2];
            float wa = wp[0], wb = wp[1], wc = wp[2];
            const _Float16* pa = P2 + (size_t)ia * C1 + n0 + cg * 16;
            const _Float16* pb = P2 + (size_t)ib * C1 + n0 + cg * 16;
            const _Float16* pc = P2 + (size_t)ic * C1 + n0 + cg * 16;
            f16x8 va0 = *(const f16x8*)pa, va1 = *(const f16x8*)(pa + 8);
            f16x8 vb0 = *(const f16x8*)pb, vb1 = *(const f16x8*)(pb + 8);
            f16x8 vc0 = *(const f16x8*)pc, vc1 = *(const f16x8*)(pc + 8);
            float g[16];
#pragma unroll
            for (int i = 0; i < 8; ++i) {
                g[i]     = wa * (float)va0[i] + wb * (float)vb0[i] + wc * (float)vc0[i];
                g[8 + i] = wa * (float)va1[i] + wb * (float)vb1[i] + wc * (float)vc1[i];
            }
#pragma unroll
            for (int i = 0; i < 4; ++i) {
                float4 t4 = make_float4(g[i*4+0], g[i*4+1], g[i*4+2], g[i*4+3]);
                *(float4*)&G[rg * GSTRIDE + cg * 16 + i * 4] = t4;
            }
            __syncthreads();                   // G[h] ready
            if (wm == h) {
#pragma unroll
                for (int mi = 0; mi < 2; ++mi)
#pragma unroll
                    for (int r = 0; r < 4; ++r) {
                        int row_l = mi * 16 + q4 * 4 + r;
#pragma unroll
                        for (int ni = 0; ni < 4; ++ni)
                            acc[mi][ni][r] += G[row_l * GSTRIDE + wn * 64 + ni * 16 + ln];
                    }
            }
            __syncthreads();                   // consumers done before next fill
        }
    }

#pragma unroll
    for (int ni = 0; ni < 4; ++ni) {
        int col = n0 + wn * 64 + ni * 16 + ln;
        float vb = bias ? bias[col] : 0.0f;
        float s = 0.0f, s2 = 0.0f;
#pragma unroll
        for (int mi = 0; mi < 2; ++mi) {
#pragma unroll
            for (int r = 0; r < 4; ++r) {
                int row_g = m0 + wm * 32 + mi * 16 + q4 * 4 + r;
                float v = acc[mi][ni][r] + vb;
                if constexpr (NT) {
                    __builtin_nontemporal_store((OT)v, &C[(size_t)row_g * ldc + col]);
                } else {
                    C[(size_t)row_g * ldc + col] = (OT)v;
                }
                s += v; s2 += v * v;
            }
        }
        if (FUSE_STATS) {
            s  += __shfl_xor(s, 16);  s  += __shfl_xor(s, 32);
            s2 += __shfl_xor(s2, 16); s2 += __shfl_xor(s2, 32);
            if (q4 == 0) {
                // coalesced partial: slot layout [logical][wave][ni][ln]
                pstatO[(size_t)logical * 256 + wave * 64 + ni * 16 + ln] =
                    make_float2(s, s2);
            }
        }
    }
}

// ---------------------------------------------------------------------------
// Fold per-block stat partials into sum/sq. Slot layout matches the GEMM
// writer: t = wave*64 + ni*16 + ln; col = half*128 + (wave>>1)*64 + ni*16+ln.
// ---------------------------------------------------------------------------
__global__ __launch_bounds__(256) void stats_reduce_kernel(
    const float2* __restrict__ pstat, int nxblk, int mper,
    float* __restrict__ sumO, float* __restrict__ sqO)
{
    const int bper = nxblk / mper;
    const int half = blockIdx.x / bper;
    const int mb0  = (blockIdx.x % bper) * mper;
    const int t = threadIdx.x;
    float s = 0.0f, s2 = 0.0f;
    for (int mb = mb0; mb < mb0 + mper; ++mb) {
        float2 v = pstat[(size_t)(half * nxblk + mb) * 256 + t];
        s += v.x; s2 += v.y;
    }
    const int wave = t >> 6, wn = wave >> 1, ni = (t >> 4) & 3, ln = t & 15;
    const int col = half * 128 + wn * 64 + ni * 16 + ln;
    atomicAdd(&sumO[col], s);
    atomicAdd(&sqO[col], s2);
}

// ---------------------------------------------------------------------------
__global__ void finalize_kernel(
    const float* __restrict__ sum, const float* __restrict__ sumsq,
    const float* __restrict__ g, const float* __restrict__ beta,
    int M, int C, float* __restrict__ scale, float* __restrict__ shift)
{
    int c = threadIdx.x;
    if (c >= C) return;
    float invM = 1.0f / (float)M;
    float mean = sum[c] * invM;
    float var = fmaxf(sumsq[c] * invM - mean * mean, 0.0f);
    float rstd = 1.0f / sqrtf(var + 1e-5f);
    float sc = g[c] * rstd;
    scale[c] = sc;
    shift[c] = beta[c] - mean * sc;
}

// float4-vectorized BN+ReLU (C2=128 divides 4; i*4 never crosses a row's
// channel boundary misalignment since C % 4 == 0).
__global__ __launch_bounds__(256) void bnrelu_kernel(
    float* __restrict__ X, int total, int C,
    const float* __restrict__ scale, const float* __restrict__ shift)
{
    int i = (blockIdx.x * 256 + threadIdx.x) * 4;
    if (i >= total) return;
    int c = i & (C - 1);
    float4 v = *(float4*)&X[i];
    v.x = fmaxf(v.x * scale[c+0] + shift[c+0], 0.0f);
    v.y = fmaxf(v.y * scale[c+1] + shift[c+1], 0.0f);
    v.z = fmaxf(v.z * scale[c+2] + shift[c+2], 0.0f);
    v.w = fmaxf(v.w * scale[c+3] + shift[c+3], 0.0f);
    *(float4*)&X[i] = v;
}

// ---------------------------------------------------------------------------
extern "C" void kernel_launch(void* const* d_in, const int* in_sizes, int n_in,
                              void* d_out, int out_size, void* d_ws, size_t ws_size,
                              hipStream_t stream) {
    const float* xyz1    = (const float*)d_in[0];
    const float* xyz2    = (const float*)d_in[1];
    const float* points1 = (const float*)d_in[2];
    const float* points2 = (const float*)d_in[3];
    const float* W1      = (const float*)d_in[4];
    const float* b1      = (const float*)d_in[5];
    const float* g1      = (const float*)d_in[6];
    const float* beta1   = (const float*)d_in[7];
    const float* W2      = (const float*)d_in[8];
    const float* b2      = (const float*)d_in[9];
    const float* g2      = (const float*)d_in[10];
    const float* beta2   = (const float*)d_in[11];
    float* out = (float*)d_out;

    // ws layout (byte offsets, 16B-aligned)
    char* ws = (char*)d_ws;
    size_t off = 0;
    int*   idx = (int*)(ws + off);            off += (size_t)MTOT*3*4;
    float* w   = (float*)(ws + off);          off += (size_t)MTOT*3*4;
    _Float16* P2h = (_Float16*)(ws + off);    off += (size_t)BB*SS*C1*2;    // 8 MB
    _Float16* y1h = (_Float16*)(ws + off);    off += (size_t)MTOT*C1*2;     // 32 MB
    float* stats = (float*)(ws + off);        off += 2048*4;
    float* sum1 = stats;            // 256
    float* sq1  = stats + 256;      // 256
    float* sum2 = stats + 512;      // 128
    float* sq2  = stats + 640;      // 128
    float* scale1 = stats + 768;    // 256
    float* shift1 = stats + 1024;   // 256
    float* scale2 = stats + 1280;   // 128
    float* shift2 = stats + 1408;   // 128
    float4* packed = (float4*)(ws + off);     off += (size_t)BB*SS*16;      // 1 MB
    float* pxp = (float*)(ws + off);          off += (size_t)BB*SS*4;       // 256 KB
    float* pyp = (float*)(ws + off);          off += (size_t)BB*SS*4;
    float* pzp = (float*)(ws + off);          off += (size_t)BB*SS*4;
    float* pwp = (float*)(ws + off);          off += (size_t)BB*SS*4;
    _Float16* W1c = (_Float16*)(ws + off);    off += (size_t)C1*(D1+D2)*2;
    _Float16* W2c = (_Float16*)(ws + off);    off += (size_t)C2*C1*2;
    off = (off + 255) & ~(size_t)255;
    float2* pstat = (float2*)(ws + off);      off += (size_t)2048*256*8;    // 4 MB
    // knn partials alias the y1h region (32 MB; y1h written later in stream
    // order): pdist = NCH*3*MTOT floats (12.6 MB) at +0, dmeta (1 MB) at +20MB.
    float*  pdist = (float*)y1h;
    float4* dmeta = (float4*)((char*)y1h + (size_t)20*1024*1024);

    hipMemsetAsync(stats, 0, 768 * sizeof(float), stream);

    pack_kernel<<<(BB*SS)/256, 256, 0, stream>>>(xyz2, packed, pxp, pyp, pzp, pwp);
    wcvt_kernel<<<(C1*(D1+D2))/256, 256, 0, stream>>>(W1, W2, W1c, W2c);

    knn3_partial_kernel<<<BB * (NN/(256*QPT)) * NCH, 256, 0, stream>>>(
        xyz1, packed, pxp, pyp, pzp, pwp, pdist);
    knn3_merge_kernel<<<MTOT/256, 256, 0, stream>>>(pdist, w, dmeta);
    knn3_rescan_kernel<<<MTOT/4, 256, 0, stream>>>(xyz1, packed, dmeta, idx);

    // P2 = points2 @ W1[:,128:]^T   [B*S x 256], K=256, f16 out
    gemm_mfma_kernel<256, float, _Float16, false, false, false, false>
        <<<256*2, 256, 0, stream>>>(
        points2, D2, W1c + D1, D1 + D2, P2h, C1, 256,
        nullptr, nullptr, nullptr, nullptr, nullptr, nullptr, nullptr);

    // y1 = points1 @ W1[:,:128]^T + b1 + interp;  f16 out; partial stats
    gemm_mfma_kernel<128, float, _Float16, false, true, true, false>
        <<<1024*2, 256, 0, stream>>>(
        points1, D1, W1c, D1 + D2, y1h, C1, 1024,
        b1, nullptr, nullptr, P2h, idx, w, pstat);

    stats_reduce_kernel<<<32, 256, 0, stream>>>(pstat, 1024, 64, sum1, sq1);
    finalize_kernel<<<1, 256, 0, stream>>>(sum1, sq1, g1, beta1, MTOT, C1, scale1, shift1);

    // out = relu(bn1(y1)) @ W2^T + b2;  fp32 out; partial stats
    gemm_mfma_kernel<256, _Float16, float, true, false, true, false>
        <<<1024*1, 256, 0, stream>>>(
        y1h, C1, W2c, C1, out, C2, 1024,
        b2, scale1, shift1, nullptr, nullptr, nullptr, pstat);

    stats_reduce_kernel<<<16, 256, 0, stream>>>(pstat, 1024, 64, sum2, sq2);
    finalize_kernel<<<1, 128, 0, stream>>>(sum2, sq2, g2, beta2, MTOT, C2, scale2, shift2);
    bnrelu_kernel<<<(MTOT*C2)/(256*4), 256, 0, stream>>>(out, MTOT*C2, C2, scale2, shift2);
}